// Round 2
// baseline (85.234 us; speedup 1.0000x reference)
//
#include <hip/hip_runtime.h>
#include <cmath>

#define BB 8
#define MM 32
#define CC 80
#define AA 65536  // GRID*GRID*4

__device__ __forceinline__ float fast_rcp(float x) { return __builtin_amdgcn_rcpf(x); }

__global__ __launch_bounds__(256) void det_main(
    const float* __restrict__ logits,
    const float* __restrict__ anchors,
    const float* __restrict__ boxes,
    const int* __restrict__ labels_idx,
    float* __restrict__ out,   // [0]=loss (finalize), [1 .. B*A]=conf, [1+B*A ..]=argmax(as float)
    float* __restrict__ ws)    // ws[0]=loss_sum, ws[1]=num_pos
{
    __shared__ float s_boxes[MM * 4];
    __shared__ int   s_lab[MM];
    __shared__ float s_part[4 * 2];   // 4 waves x {loss, cnt}

    const int b = blockIdx.x >> 8;
    const int a = ((blockIdx.x & 255) << 8) | threadIdx.x;

    if (threadIdx.x < MM * 4) s_boxes[threadIdx.x] = boxes[b * MM * 4 + threadIdx.x];
    if (threadIdx.x < MM)     s_lab[threadIdx.x]   = labels_idx[b * MM + threadIdx.x];
    __syncthreads();

    // ---- IoU assignment (anchor a vs 32 boxes of batch b) ----
    const float4 anc = ((const float4*)anchors)[a];
    const float area_a = (anc.z - anc.x) * (anc.w - anc.y);
    float max_iou = -1.0f;
    int   assign  = 0;
    #pragma unroll
    for (int m = 0; m < MM; ++m) {
        const float bx1 = s_boxes[m * 4 + 0], by1 = s_boxes[m * 4 + 1];
        const float bx2 = s_boxes[m * 4 + 2], by2 = s_boxes[m * 4 + 3];
        const float w = fmaxf(fminf(anc.z, bx2) - fmaxf(anc.x, bx1), 0.0f);
        const float h = fmaxf(fminf(anc.w, by2) - fmaxf(anc.y, by1), 0.0f);
        const float inter = w * h;
        const float uni = area_a + (bx2 - bx1) * (by2 - by1) - inter;
        // uni > 0 always here (boxes have positive area); iou = inter/uni
        const float iou = inter * fast_rcp(uni);
        const bool gt = iou > max_iou;        // strict > keeps first-max (argmax semantics)
        max_iou = gt ? iou : max_iou;
        assign  = gt ? m : assign;
    }
    const bool pos     = (max_iou >= 0.5f);
    const bool neg     = (max_iou < 0.1f);
    const bool labeled = pos || neg;
    const int  tc      = pos ? s_lab[assign] : -1;

    // ---- stream the 80-logit row: max/argmax + focal BCE (all-t=0 + target correction) ----
    const float4* row = (const float4*)(logits + ((size_t)b * AA + (size_t)a) * CC);
    float mx   = -INFINITY;
    int   amx  = 0;
    float loss = 0.0f;
    float l_tc = 0.0f;
    #pragma unroll 4
    for (int k = 0; k < CC / 4; ++k) {
        const float4 v = row[k];
        const float lv[4] = {v.x, v.y, v.z, v.w};
        #pragma unroll
        for (int j = 0; j < 4; ++j) {
            const int c = k * 4 + j;
            const float l = lv[j];
            const bool gt = l > mx;
            mx  = gt ? l : mx;
            amx = gt ? c : amx;
            const float e  = __expf(-fabsf(l));      // exp(-|l|)
            const float s  = 1.0f + e;
            const float lp = __logf(s);              // log(1+e^-|l|)
            const float r  = fast_rcp(s);
            const float p  = (l >= 0.0f) ? r : e * r; // sigmoid(l)
            const float bce0 = fmaxf(l, 0.0f) + lp;   // BCE with t=0
            loss = fmaf(bce0 * p, p, loss);           // + bce0 * p^2
            l_tc = (c == tc) ? l : l_tc;
        }
    }
    // correction for the single target class (t=1 instead of t=0)
    if (tc >= 0) {
        const float l  = l_tc;
        const float e  = __expf(-fabsf(l));
        const float s  = 1.0f + e;
        const float lp = __logf(s);
        const float r  = fast_rcp(s);
        const float p  = (l >= 0.0f) ? r : e * r;
        const float bce0 = fmaxf(l, 0.0f) + lp;
        const float bce1 = bce0 - l;                  // BCE with t=1
        const float d1   = 1.0f - p;
        loss += bce1 * d1 * d1 - bce0 * p * p;
    }

    // ---- outputs ----
    const size_t ba = (size_t)b * AA + (size_t)a;
    {
        const float e = __expf(-fabsf(mx));
        const float r = fast_rcp(1.0f + e);
        out[1 + ba] = (mx >= 0.0f) ? r : e * r;       // sigmoid(max logit) == max prob
    }
    out[1 + (size_t)BB * AA + ba] = (float)amx;

    // ---- reduce {labeled loss, pos count}: wave shuffle then 4 partials ----
    float rl = labeled ? loss : 0.0f;
    float rc = pos ? 1.0f : 0.0f;
    #pragma unroll
    for (int off = 32; off > 0; off >>= 1) {
        rl += __shfl_down(rl, off, 64);
        rc += __shfl_down(rc, off, 64);
    }
    const int wave = threadIdx.x >> 6;
    if ((threadIdx.x & 63) == 0) { s_part[wave * 2] = rl; s_part[wave * 2 + 1] = rc; }
    __syncthreads();
    if (threadIdx.x == 0) {
        float tl = s_part[0] + s_part[2] + s_part[4] + s_part[6];
        float tcnt = s_part[1] + s_part[3] + s_part[5] + s_part[7];
        atomicAdd(&ws[0], tl);
        atomicAdd(&ws[1], tcnt);
    }
}

__global__ void det_final(const float* __restrict__ ws, float* __restrict__ out) {
    out[0] = ws[0] / ws[1];
}

extern "C" void kernel_launch(void* const* d_in, const int* in_sizes, int n_in,
                              void* d_out, int out_size, void* d_ws, size_t ws_size,
                              hipStream_t stream) {
    const float* logits     = (const float*)d_in[0];
    const float* anchors    = (const float*)d_in[1];
    const float* boxes      = (const float*)d_in[2];
    // d_in[3] (one-hot labels) unused: gather(labels, assign) == one_hot(labels_idx[assign])
    const int*   labels_idx = (const int*)d_in[4];
    float* out = (float*)d_out;
    float* ws  = (float*)d_ws;

    hipMemsetAsync(ws, 0, 2 * sizeof(float), stream);
    det_main<<<dim3((BB * AA) / 256), dim3(256), 0, stream>>>(logits, anchors, boxes, labels_idx, out, ws);
    det_final<<<1, 1, 0, stream>>>(ws, out);
}